// Round 1
// baseline (75.735 us; speedup 1.0000x reference)
//
#include <hip/hip_runtime.h>
#include <hip/hip_bf16.h>
#include <stdint.h>

typedef short bf16x8 __attribute__((ext_vector_type(8)));
typedef float f32x4 __attribute__((ext_vector_type(4)));

#define D  512
#define NB 4096
#define NT 8192

__device__ __forceinline__ unsigned short f2bf(float f) {
    __hip_bfloat16 h = __float2bfloat16(f);
    return *reinterpret_cast<unsigned short*>(&h);
}

// Fused fp32->bf16 convert + row squared-norm. One wave per row (512 elems, 8/lane).
__global__ __launch_bounds__(256) void prep_kernel(
    const float* __restrict__ src, unsigned short* __restrict__ dst,
    float* __restrict__ norms, int nrows)
{
    const int row  = blockIdx.x * 4 + (threadIdx.x >> 6);
    const int lane = threadIdx.x & 63;
    const float4* rp = reinterpret_cast<const float4*>(src + (size_t)row * D);
    float4 v0 = rp[lane * 2];
    float4 v1 = rp[lane * 2 + 1];
    float s = v0.x*v0.x + v0.y*v0.y + v0.z*v0.z + v0.w*v0.w
            + v1.x*v1.x + v1.y*v1.y + v1.z*v1.z + v1.w*v1.w;
    union { unsigned short h[8]; int4 v; } u;
    u.h[0] = f2bf(v0.x); u.h[1] = f2bf(v0.y); u.h[2] = f2bf(v0.z); u.h[3] = f2bf(v0.w);
    u.h[4] = f2bf(v1.x); u.h[5] = f2bf(v1.y); u.h[6] = f2bf(v1.z); u.h[7] = f2bf(v1.w);
    reinterpret_cast<int4*>(dst + (size_t)row * D)[lane] = u.v;
    #pragma unroll
    for (int off = 32; off > 0; off >>= 1) s += __shfl_xor(s, off);
    if (lane == 0) norms[row] = s;
}

// 128x128 tile, BK=64, 4 waves (2x2), 16x16x32 bf16 MFMA.
// global_load_lds width-16 staging with inverse-swizzled global source
// (rule #21): LDS[row][c'] holds global chunk c' ^ (row&7); ds_read applies
// the same XOR -> ~2-way (free) bank aliasing instead of 16-way.
__global__ __launch_bounds__(256) void gemm_sim_kernel(
    const unsigned short* __restrict__ X, const unsigned short* __restrict__ Y,
    const float* __restrict__ x2, const float* __restrict__ y2,
    float* __restrict__ out)
{
    __shared__ alignas(16) unsigned short As[128 * 64];
    __shared__ alignas(16) unsigned short Bs[128 * 64];

    const int tid  = threadIdx.x;
    const int lane = tid & 63;
    const int wid  = tid >> 6;
    const int wr   = wid >> 1;
    const int wc   = wid & 1;

    const int rowBase = blockIdx.x * 128;
    const int colBase = blockIdx.y * 128;

    f32x4 acc[4][4] = {};

    // Staging map: thread covers LDS linear bytes L = i*4096 + tid*16.
    // row = i*32 + (tid>>3), stored chunk c' = tid&7, global chunk = c'^(row&7).
    const int rA = tid >> 3;                 // 0..31
    const int cg = (tid & 7) ^ (rA & 7);     // global 16B-chunk index, 0..7
    const unsigned short* gA = X + (size_t)(rowBase + rA) * D + cg * 8;
    const unsigned short* gB = Y + (size_t)(colBase + rA) * D + cg * 8;
    unsigned short* lA = As + wid * 512;     // wave-uniform LDS base (bytes: wid*1024)
    unsigned short* lB = Bs + wid * 512;

    for (int kt = 0; kt < D / 64; ++kt) {
        #pragma unroll
        for (int i = 0; i < 4; ++i) {
            __builtin_amdgcn_global_load_lds(
                (const __attribute__((address_space(1))) void*)(gA + (size_t)i * 32 * D + kt * 64),
                (__attribute__((address_space(3))) void*)(lA + i * 2048), 16, 0, 0);
            __builtin_amdgcn_global_load_lds(
                (const __attribute__((address_space(1))) void*)(gB + (size_t)i * 32 * D + kt * 64),
                (__attribute__((address_space(3))) void*)(lB + i * 2048), 16, 0, 0);
        }
        __syncthreads();

        #pragma unroll
        for (int kk = 0; kk < 2; ++kk) {
            const int kchunk = kk * 4 + (lane >> 4);  // global 16B k-chunk this lane needs
            bf16x8 a[4], b[4];
            #pragma unroll
            for (int m = 0; m < 4; ++m) {
                int r = wr * 64 + m * 16 + (lane & 15);
                a[m] = *reinterpret_cast<const bf16x8*>(As + r * 64 + (kchunk ^ (r & 7)) * 8);
            }
            #pragma unroll
            for (int n = 0; n < 4; ++n) {
                int r = wc * 64 + n * 16 + (lane & 15);
                b[n] = *reinterpret_cast<const bf16x8*>(Bs + r * 64 + (kchunk ^ (r & 7)) * 8);
            }
            #pragma unroll
            for (int m = 0; m < 4; ++m)
                #pragma unroll
                for (int n = 0; n < 4; ++n)
                    acc[m][n] = __builtin_amdgcn_mfma_f32_16x16x32_bf16(a[m], b[n], acc[m][n], 0, 0, 0);
        }
        __syncthreads();
    }

    // Epilogue: C/D layout col = lane&15, row = (lane>>4)*4 + reg  [m89/m91].
    const int col0 = colBase + wc * 64 + (lane & 15);
    const int row0 = rowBase + wr * 64 + ((lane >> 4) << 2);
    #pragma unroll
    for (int m = 0; m < 4; ++m) {
        #pragma unroll
        for (int q = 0; q < 4; ++q) {
            const int grow = row0 + m * 16 + q;
            const float xn = x2[grow];
            float* orow = out + (size_t)grow * NT;
            #pragma unroll
            for (int n = 0; n < 4; ++n) {
                const int gcol = col0 + n * 16;
                float sq = xn + y2[gcol] - 2.0f * acc[m][n][q];
                sq = fmaxf(sq, 0.0f);
                float sim = fminf(rsqrtf(sq), 1.0e6f);  // rsqrt(0)=inf -> clipped to 1e6
                orow[gcol] = sim;
            }
        }
    }
}

extern "C" void kernel_launch(void* const* d_in, const int* in_sizes, int n_in,
                              void* d_out, int out_size, void* d_ws, size_t ws_size,
                              hipStream_t stream)
{
    const float* x = (const float*)d_in[0];
    const float* y = (const float*)d_in[1];
    float* out = (float*)d_out;
    char* ws = (char*)d_ws;

    unsigned short* xb = (unsigned short*)ws;                 // 4 MB
    unsigned short* yb = (unsigned short*)(ws + (4u << 20));  // 8 MB
    float* x2 = (float*)(ws + (12u << 20));                   // 16 KB
    float* y2 = (float*)(ws + (12u << 20) + 4 * NB);          // 32 KB

    // Output 0: passthrough copy of base_features.
    hipMemcpyAsync(out, x, (size_t)NB * D * sizeof(float),
                   hipMemcpyDeviceToDevice, stream);

    prep_kernel<<<NB / 4, 256, 0, stream>>>(x, xb, x2, NB);
    prep_kernel<<<NT / 4, 256, 0, stream>>>(y, yb, y2, NT);

    dim3 grid(NB / 128, NT / 128);
    gemm_sim_kernel<<<grid, 256, 0, stream>>>(xb, yb, x2, y2, out + (size_t)NB * D);
}

// Round 2
// 68.967 us; speedup vs baseline: 1.0981x; 1.0981x over previous
//
#include <hip/hip_runtime.h>
#include <hip/hip_bf16.h>
#include <stdint.h>

typedef short bf16x8 __attribute__((ext_vector_type(8)));
typedef float f32x4 __attribute__((ext_vector_type(4)));

#define D  512
#define NB 4096
#define NT 8192

__device__ __forceinline__ unsigned short f2bf(float f) {
    __hip_bfloat16 h = __float2bfloat16(f);
    return *reinterpret_cast<unsigned short*>(&h);
}

// Fused fp32->bf16 convert + row squared-norm (+ optional fp32 passthrough copy).
__global__ __launch_bounds__(256) void prep_kernel(
    const float* __restrict__ src, unsigned short* __restrict__ dst,
    float* __restrict__ norms, float* __restrict__ copy)
{
    const int row  = blockIdx.x * 4 + (threadIdx.x >> 6);
    const int lane = threadIdx.x & 63;
    const float4* rp = reinterpret_cast<const float4*>(src + (size_t)row * D);
    float4 v0 = rp[lane * 2];
    float4 v1 = rp[lane * 2 + 1];
    if (copy) {
        float4* cp = reinterpret_cast<float4*>(copy + (size_t)row * D);
        cp[lane * 2]     = v0;
        cp[lane * 2 + 1] = v1;
    }
    float s = v0.x*v0.x + v0.y*v0.y + v0.z*v0.z + v0.w*v0.w
            + v1.x*v1.x + v1.y*v1.y + v1.z*v1.z + v1.w*v1.w;
    union { unsigned short h[8]; int4 v; } u;
    u.h[0] = f2bf(v0.x); u.h[1] = f2bf(v0.y); u.h[2] = f2bf(v0.z); u.h[3] = f2bf(v0.w);
    u.h[4] = f2bf(v1.x); u.h[5] = f2bf(v1.y); u.h[6] = f2bf(v1.z); u.h[7] = f2bf(v1.w);
    reinterpret_cast<int4*>(dst + (size_t)row * D)[lane] = u.v;
    #pragma unroll
    for (int off = 32; off > 0; off >>= 1) s += __shfl_xor(s, off);
    if (lane == 0) norms[row] = s;
}

// 256x256 tile, BK=64, 8 waves (2Mx4N), 8-phase counted-vmcnt schedule
// (T2 swizzle + T3/T4 pipeline + T5 setprio). LDS: 2 buffers x {A,B} x
// {ks0,ks1} half-tiles of 256x32 bf16 (16 KiB each) = 128 KiB.
// Region base (ushort): REGN(buf, mat, ks).
#define REGN(b, mat, ks) ((b) * 32768 + (mat) * 16384 + (ks) * 8192)

__global__ __launch_bounds__(512, 2) void gemm_sim_kernel(
    const unsigned short* __restrict__ X, const unsigned short* __restrict__ Y,
    const float* __restrict__ x2, const float* __restrict__ y2,
    float* __restrict__ out)
{
    __shared__ alignas(16) unsigned short lds[65536];   // 128 KiB

    const int tid  = threadIdx.x;
    const int lane = tid & 63;
    const int w    = tid >> 6;
    const int wr   = w >> 2;    // 0..1  (wave row, 128 rows each)
    const int wc   = w & 3;     // 0..3  (wave col, 64 cols each)

    // XCD-aware block swizzle: 512 blocks, 8 XCDs, 64 contiguous per XCD.
    const int bid = blockIdx.x;
    const int swz = (bid & 7) * 64 + (bid >> 3);
    const int rowBase = (swz & 15) * 256;
    const int colBase = (swz >> 4) * 256;

    // Staging (write) side: thread t covers LDS bytes t*16 (+L*8192) of a
    // linear 256x32 half-tile. Source chunk pre-swizzled (rule #21) so the
    // read side can XOR-deswizzle for bank-conflict-free ds_read_b128.
    const int rst = tid >> 2;                      // row 0..127 (L=1 adds 128)
    const int gst = (tid & 3) ^ ((rst >> 1) & 3);  // global 16B chunk 0..3
    const unsigned short* gA = X + (size_t)(rowBase + rst) * D + gst * 8;
    const unsigned short* gB = Y + (size_t)(colBase + rst) * D + gst * 8;
    const int ldst = w * 512;                      // wave-uniform LDS base (ushort)

    // Read side: swizzled chunk index folds to a per-lane constant.
    const int cread = ((lane >> 4) ^ ((lane >> 1) & 3)) * 8;
    const int aoff = (wr * 128 + (lane & 15)) * 32 + cread;
    const int boff = (wc * 64  + (lane & 15)) * 32 + cread;

    f32x4 acc[8][4] = {};
    bf16x8 bfr[4];

#define STAGE(BUF, MAT, KS, KT) do { \
    const unsigned short* _g = ((MAT) ? gB : gA) + (KT) * 64 + (KS) * 32; \
    const int _l = REGN(BUF, MAT, KS) + ldst; \
    __builtin_amdgcn_global_load_lds((const __attribute__((address_space(1))) void*)_g, \
        (__attribute__((address_space(3))) void*)(lds + _l), 16, 0, 0); \
    __builtin_amdgcn_global_load_lds((const __attribute__((address_space(1))) void*)(_g + 128 * D), \
        (__attribute__((address_space(3))) void*)(lds + _l + 4096), 16, 0, 0); \
} while (0)

#define PHASE(BUF, KS, MH, STG, CKPT) do { \
    bf16x8 _a[4]; \
    if ((MH) == 0) { \
        _Pragma("unroll") \
        for (int n = 0; n < 4; ++n) \
            bfr[n] = *(const bf16x8*)(lds + REGN(BUF, 1, KS) + boff + n * 512); \
    } \
    _Pragma("unroll") \
    for (int m = 0; m < 4; ++m) \
        _a[m] = *(const bf16x8*)(lds + REGN(BUF, 0, KS) + aoff + (MH) * 2048 + m * 512); \
    STG; \
    asm volatile("s_barrier" ::: "memory"); \
    asm volatile("s_waitcnt lgkmcnt(0)" ::: "memory"); \
    __builtin_amdgcn_s_setprio(1); \
    _Pragma("unroll") \
    for (int m = 0; m < 4; ++m) { \
        _Pragma("unroll") \
        for (int n = 0; n < 4; ++n) \
            acc[(MH) * 4 + m][n] = __builtin_amdgcn_mfma_f32_16x16x32_bf16(_a[m], bfr[n], acc[(MH) * 4 + m][n], 0, 0, 0); \
    } \
    __builtin_amdgcn_s_setprio(0); \
    CKPT; \
    asm volatile("s_barrier" ::: "memory"); \
} while (0)

    // Prologue: tile0 full (buf0: A-ks0, B-ks0, A-ks1, B-ks1), tile1 ks0 (buf1).
    STAGE(0, 0, 0, 0); STAGE(0, 1, 0, 0); STAGE(0, 0, 1, 0); STAGE(0, 1, 1, 0);
    STAGE(1, 0, 0, 1); STAGE(1, 1, 0, 1);
    asm volatile("s_waitcnt vmcnt(4)" ::: "memory");   // tile0's 8 loads landed
    asm volatile("s_barrier" ::: "memory");

    // 4 iterations x 2 K-tiles (K=512, BK=64 -> 8 K-tiles).
    // Stage slots (race-screened): p0/p1 -> buf1.ks1 (tile 2j+1);
    // p2..p5 -> buf0 (tile 2j+2); p6/p7 -> buf1.ks0 (tile 2j+3).
    // Checkpoints: end of p3 and p7, vmcnt(4) steady / vmcnt(0) final p3.
#pragma unroll
    for (int j = 0; j < 4; ++j) {
        const int t1 = 2 * j + 1, t2 = 2 * j + 2, t3 = 2 * j + 3;
        PHASE(0, 0, 0, STAGE(1, 0, 1, t1), ((void)0));
        PHASE(0, 0, 1, STAGE(1, 1, 1, t1), ((void)0));
        PHASE(0, 1, 0, if (t2 < 8) STAGE(0, 0, 0, t2), ((void)0));
        PHASE(0, 1, 1, if (t2 < 8) STAGE(0, 1, 0, t2),
              if (j < 3) { asm volatile("s_waitcnt vmcnt(4)" ::: "memory"); }
              else       { asm volatile("s_waitcnt vmcnt(0)" ::: "memory"); });
        PHASE(1, 0, 0, if (t2 < 8) STAGE(0, 0, 1, t2), ((void)0));
        PHASE(1, 0, 1, if (t2 < 8) STAGE(0, 1, 1, t2), ((void)0));
        PHASE(1, 1, 0, if (t3 < 8) STAGE(1, 0, 0, t3), ((void)0));
        PHASE(1, 1, 1, if (t3 < 8) STAGE(1, 1, 0, t3),
              if (j < 3) { asm volatile("s_waitcnt vmcnt(4)" ::: "memory"); });
    }
#undef PHASE
#undef STAGE

    // Epilogue: C/D layout col = lane&15, row = (lane>>4)*4 + reg.
    const int col0 = colBase + wc * 64 + (lane & 15);
    const int row0 = rowBase + wr * 128 + ((lane >> 4) << 2);
    #pragma unroll
    for (int mi = 0; mi < 8; ++mi) {
        const int rbase = row0 + (mi >> 2) * 64 + (mi & 3) * 16;
        #pragma unroll
        for (int q = 0; q < 4; ++q) {
            const int grow = rbase + q;
            const float xn = x2[grow];
            float* orow = out + (size_t)grow * NT;
            #pragma unroll
            for (int n = 0; n < 4; ++n) {
                const int gcol = col0 + n * 16;
                float sq = fmaxf(xn + y2[gcol] - 2.0f * acc[mi][n][q], 0.0f);
                orow[gcol] = fminf(rsqrtf(sq), 1.0e6f);  // rsqrt(0)=inf -> clipped
            }
        }
    }
}

extern "C" void kernel_launch(void* const* d_in, const int* in_sizes, int n_in,
                              void* d_out, int out_size, void* d_ws, size_t ws_size,
                              hipStream_t stream)
{
    const float* x = (const float*)d_in[0];
    const float* y = (const float*)d_in[1];
    float* out = (float*)d_out;
    char* ws = (char*)d_ws;

    unsigned short* xb = (unsigned short*)ws;                 // 4 MB
    unsigned short* yb = (unsigned short*)(ws + (4u << 20));  // 8 MB
    float* x2 = (float*)(ws + (12u << 20));                   // 16 KB
    float* y2 = (float*)(ws + (12u << 20) + 4 * NB);          // 32 KB

    // prep_x also writes the base_features passthrough (output 0).
    prep_kernel<<<NB / 4, 256, 0, stream>>>(x, xb, x2, out);
    prep_kernel<<<NT / 4, 256, 0, stream>>>(y, yb, y2, nullptr);

    gemm_sim_kernel<<<512, 512, 0, stream>>>(xb, yb, x2, y2, out + (size_t)NB * D);
}